// Round 2
// baseline (587.952 us; speedup 1.0000x reference)
//
#include <hip/hip_runtime.h>
#include <hip/hip_bf16.h>

// Kernel A: per g-edge, pack (color[src]<<2)|color[dst] into one byte.
__global__ void pack_edge_colors_kernel(const int* __restrict__ src_g,
                                        const int* __restrict__ dst_g,
                                        const int* __restrict__ h_nodes,
                                        unsigned char* __restrict__ pc,
                                        int eg) {
    int stride = gridDim.x * blockDim.x;
    for (int e = blockIdx.x * blockDim.x + threadIdx.x; e < eg; e += stride) {
        int hs = h_nodes[src_g[e]];
        int hd = h_nodes[dst_g[e]];
        pc[e] = (unsigned char)((hs << 2) | hd);
    }
}

// Kernel B: per h-edge, derive 3-bit combo from two packed-color gathers and
// copy the matching precomputed 64-float row (8x64 table in LDS) to output.
// 16 lanes per row, float4 stores -> each 256-thread iteration writes a
// contiguous 4KB run.
__global__ void __launch_bounds__(256)
triplet_out_kernel(const int* __restrict__ src_h,
                   const int* __restrict__ dst_h,
                   const unsigned char* __restrict__ pc,
                   const float* __restrict__ e1,
                   const float* __restrict__ e2,
                   const float* __restrict__ e3,
                   float4* __restrict__ out4,
                   int eh) {
    __shared__ float table[8 * 64];   // 2 KB: all 8 possible output rows

    // Build the 8-row table once per block (amortized over grid-stride loop).
    for (int i = threadIdx.x; i < 8 * 64; i += blockDim.x) {
        int combo = i >> 6;           // hac*4 + hab*2 + hbc
        int f     = i & 63;
        float v = e1[((combo >> 2) & 1) * 64 + f]
                + e2[((combo >> 1) & 1) * 64 + f]
                + e3[( combo       & 1) * 64 + f];
        table[combo * 64 + f] = v;
    }
    __syncthreads();

    const float4* table4 = (const float4*)table;

    const int rows_per_blk = blockDim.x >> 4;          // 16 rows / iteration
    const int lane16 = threadIdx.x & 15;               // float4 slot in row
    const int rgrp   = threadIdx.x >> 4;               // which row in tile
    const long long ntiles = ((long long)eh + rows_per_blk - 1) / rows_per_blk;

    for (long long tile = blockIdx.x; tile < ntiles; tile += gridDim.x) {
        long long row = tile * rows_per_blk + rgrp;
        if (row < eh) {
            int s = src_h[row];                        // broadcast in group
            int d = dst_h[row];
            unsigned int ps = pc[s];                   // (a<<2)|b
            unsigned int pd = pc[d];                   // (?<<2)|c
            int a = (int)(ps >> 2);
            int b = (int)(ps & 3u);
            int c = (int)(pd & 3u);
            int combo = ((a == c) << 2) | ((a == b) << 1) | (int)(b == c);
            out4[row * 16 + lane16] = table4[combo * 16 + lane16];
        }
    }
}

extern "C" void kernel_launch(void* const* d_in, const int* in_sizes, int n_in,
                              void* d_out, int out_size, void* d_ws, size_t ws_size,
                              hipStream_t stream) {
    const int* h_nodes = (const int*)d_in[0];
    const int* src_g   = (const int*)d_in[1];
    const int* dst_g   = (const int*)d_in[2];
    const int* src_h   = (const int*)d_in[3];
    const int* dst_h   = (const int*)d_in[4];
    const float* e1_w  = (const float*)d_in[5];
    const float* e2_w  = (const float*)d_in[6];
    const float* e3_w  = (const float*)d_in[7];

    const int eg = in_sizes[1];   // E_G = 1,600,000
    const int eh = in_sizes[3];   // E_H = 2,000,000

    unsigned char* pc = (unsigned char*)d_ws;   // E_G bytes of scratch

    pack_edge_colors_kernel<<<2048, 256, 0, stream>>>(src_g, dst_g, h_nodes, pc, eg);

    triplet_out_kernel<<<2048, 256, 0, stream>>>(src_h, dst_h, pc,
                                                 e1_w, e2_w, e3_w,
                                                 (float4*)d_out, eh);
}

// Round 3
// 561.215 us; speedup vs baseline: 1.0476x; 1.0476x over previous
//
#include <hip/hip_runtime.h>
#include <hip/hip_bf16.h>

// Kernel A: per g-edge, pack (color[src]<<2)|color[dst] into one byte.
// Vectorized: int4 index loads, uchar4 packed store (4 edges/thread).
__global__ void __launch_bounds__(256)
pack_edge_colors_kernel(const int4* __restrict__ src_g4,
                        const int4* __restrict__ dst_g4,
                        const int* __restrict__ src_g,
                        const int* __restrict__ dst_g,
                        const int* __restrict__ h_nodes,
                        unsigned char* __restrict__ pc,
                        int eg) {
    const int n4 = eg >> 2;
    const int stride = gridDim.x * blockDim.x;
    for (int i = blockIdx.x * blockDim.x + threadIdx.x; i < n4; i += stride) {
        int4 s = src_g4[i];
        int4 d = dst_g4[i];
        uchar4 p;
        p.x = (unsigned char)((h_nodes[s.x] << 2) | h_nodes[d.x]);
        p.y = (unsigned char)((h_nodes[s.y] << 2) | h_nodes[d.y]);
        p.z = (unsigned char)((h_nodes[s.z] << 2) | h_nodes[d.z]);
        p.w = (unsigned char)((h_nodes[s.w] << 2) | h_nodes[d.w]);
        *(uchar4*)(pc + (i << 2)) = p;
    }
    // tail (eg not multiple of 4)
    int t = blockIdx.x * blockDim.x + threadIdx.x;
    int e = (n4 << 2) + t;
    if (e < eg) {
        pc[e] = (unsigned char)((h_nodes[src_g[e]] << 2) | h_nodes[dst_g[e]]);
    }
}

// Kernel B, phase-split per 256-row tile:
//   phase 1: 1 thread/row -> coalesced src_h/dst_h loads, 2 byte gathers,
//            combo byte into LDS.
//   phase 2: 256 threads stream 4096 float4 stores (16/thread, LDS-fed,
//            no dependence on global loads) -> contiguous 64 KB per tile.
#define ROWS_PER_TILE 256

__global__ void __launch_bounds__(256)
triplet_out_kernel(const int* __restrict__ src_h,
                   const int* __restrict__ dst_h,
                   const unsigned char* __restrict__ pc,
                   const float* __restrict__ e1,
                   const float* __restrict__ e2,
                   const float* __restrict__ e3,
                   float4* __restrict__ out4,
                   int eh) {
    __shared__ float table[8 * 64];                 // 2 KB: all 8 output rows
    __shared__ unsigned char combo_s[ROWS_PER_TILE];

    const int tid = threadIdx.x;

    // Build the 8-row table once per block.
    for (int i = tid; i < 8 * 64; i += blockDim.x) {
        int combo = i >> 6;                         // hac*4 + hab*2 + hbc
        int f     = i & 63;
        table[i] = e1[((combo >> 2) & 1) * 64 + f]
                 + e2[((combo >> 1) & 1) * 64 + f]
                 + e3[( combo       & 1) * 64 + f];
    }
    __syncthreads();

    const float4* table4 = (const float4*)table;

    for (long long base = (long long)blockIdx.x * ROWS_PER_TILE; base < eh;
         base += (long long)gridDim.x * ROWS_PER_TILE) {
        // ---- phase 1: combos for this tile ----
        long long row = base + tid;
        if (row < eh) {
            int s = src_h[row];                     // coalesced
            int d = dst_h[row];                     // coalesced
            unsigned int ps = pc[s];                // (a<<2)|b  byte gather
            unsigned int pd = pc[d];                // (?<<2)|c  byte gather
            int a = (int)(ps >> 2);
            int b = (int)(ps & 3u);
            int c = (int)(pd & 3u);
            combo_s[tid] =
                (unsigned char)(((a == c) << 2) | ((a == b) << 1) | (int)(b == c));
        }
        __syncthreads();

        // ---- phase 2: stream the output tile ----
        int nrows = eh - base < ROWS_PER_TILE ? (int)(eh - base) : ROWS_PER_TILE;
        int total4 = nrows << 4;                    // nrows * 16 float4
        for (int j = tid; j < total4; j += blockDim.x) {
            int rl   = j >> 4;
            int lane = j & 15;
            out4[(base + rl) * 16 + lane] = table4[combo_s[rl] * 16 + lane];
        }
        __syncthreads();                            // combo_s reused next iter
    }
}

extern "C" void kernel_launch(void* const* d_in, const int* in_sizes, int n_in,
                              void* d_out, int out_size, void* d_ws, size_t ws_size,
                              hipStream_t stream) {
    const int* h_nodes = (const int*)d_in[0];
    const int* src_g   = (const int*)d_in[1];
    const int* dst_g   = (const int*)d_in[2];
    const int* src_h   = (const int*)d_in[3];
    const int* dst_h   = (const int*)d_in[4];
    const float* e1_w  = (const float*)d_in[5];
    const float* e2_w  = (const float*)d_in[6];
    const float* e3_w  = (const float*)d_in[7];

    const int eg = in_sizes[1];   // E_G = 1,600,000
    const int eh = in_sizes[3];   // E_H = 2,000,000

    unsigned char* pc = (unsigned char*)d_ws;   // E_G bytes of scratch

    pack_edge_colors_kernel<<<2048, 256, 0, stream>>>(
        (const int4*)src_g, (const int4*)dst_g, src_g, dst_g, h_nodes, pc, eg);

    triplet_out_kernel<<<2048, 256, 0, stream>>>(src_h, dst_h, pc,
                                                 e1_w, e2_w, e3_w,
                                                 (float4*)d_out, eh);
}

// Round 8
// 558.768 us; speedup vs baseline: 1.0522x; 1.0044x over previous
//
#include <hip/hip_runtime.h>
#include <hip/hip_bf16.h>

// native clang vector types — __builtin_nontemporal_store rejects
// HIP_vector_type wrappers (uchar4*/float4*).
typedef float nfloat4 __attribute__((ext_vector_type(4)));

// Kernel A: per g-edge, pack (color[src]<<2)|color[dst] into one byte.
// int4 index loads, 4-byte packed nontemporal store (4 edges/thread).
__global__ void __launch_bounds__(256)
pack_edge_colors_kernel(const int4* __restrict__ src_g4,
                        const int4* __restrict__ dst_g4,
                        const int* __restrict__ src_g,
                        const int* __restrict__ dst_g,
                        const int* __restrict__ h_nodes,
                        unsigned char* __restrict__ pc,
                        int eg) {
    const int n4 = eg >> 2;
    const int stride = gridDim.x * blockDim.x;
    for (int i = blockIdx.x * blockDim.x + threadIdx.x; i < n4; i += stride) {
        int4 s = src_g4[i];
        int4 d = dst_g4[i];
        unsigned int p =
            (unsigned int)((h_nodes[s.x] << 2) | h_nodes[d.x])
          | ((unsigned int)((h_nodes[s.y] << 2) | h_nodes[d.y]) << 8)
          | ((unsigned int)((h_nodes[s.z] << 2) | h_nodes[d.z]) << 16)
          | ((unsigned int)((h_nodes[s.w] << 2) | h_nodes[d.w]) << 24);
        __builtin_nontemporal_store(p, (unsigned int*)(pc + (i << 2)));
    }
    int t = blockIdx.x * blockDim.x + threadIdx.x;
    int e = (n4 << 2) + t;
    if (e < eg) {
        pc[e] = (unsigned char)((h_nodes[src_g[e]] << 2) | h_nodes[dst_g[e]]);
    }
}

// Kernel B: software-pipelined tiles.
//  - tile t+1's index loads + gathers issue before tile t's store drain;
//  - stores are nontemporal (evict-first) so the 512 MB stream doesn't evict
//    the 1.6 MB pc table from L2;
//  - per tile: 2 coalesced dword loads + 2 byte gathers per row (1 thr/row),
//    then 4096 LDS-fed 16B stores (contiguous 64 KB).
#define TILE 256

__global__ void __launch_bounds__(256)
triplet_out_kernel(const int* __restrict__ src_h,
                   const int* __restrict__ dst_h,
                   const unsigned char* __restrict__ pc,
                   const float* __restrict__ e1,
                   const float* __restrict__ e2,
                   const float* __restrict__ e3,
                   float* __restrict__ out,
                   int eh) {
    __shared__ float table[8 * 64];        // 2 KB: all 8 possible output rows
    __shared__ unsigned char combo_s[TILE];

    const int tid = threadIdx.x;

    for (int i = tid; i < 8 * 64; i += blockDim.x) {
        int combo = i >> 6;                // hac*4 + hab*2 + hbc
        int f     = i & 63;
        table[i] = e1[((combo >> 2) & 1) * 64 + f]
                 + e2[((combo >> 1) & 1) * 64 + f]
                 + e3[( combo       & 1) * 64 + f];
    }

    const nfloat4* table4 = (const nfloat4*)table;
    nfloat4* out4 = (nfloat4*)out;
    const long long ntiles = ((long long)eh + TILE - 1) / TILE;

    // ---- prologue: combo for the first tile ----
    long long t = blockIdx.x;
    unsigned char my_combo = 0;
    if (t < ntiles) {
        long long row = t * TILE + tid;
        if (row < eh) {
            int s = src_h[row];
            int d = dst_h[row];
            unsigned int ps = pc[s];       // (a<<2)|b
            unsigned int pd = pc[d];       // (?<<2)|c
            int a = (int)(ps >> 2);
            int b = (int)(ps & 3u);
            int c = (int)(pd & 3u);
            my_combo = (unsigned char)(((a == c) << 2) | ((a == b) << 1) |
                                       (int)(b == c));
        }
    }
    __syncthreads();                       // table ready; combo_s free

    while (t < ntiles) {
        combo_s[tid] = my_combo;
        __syncthreads();                   // combo_s ready for this tile

        // issue next tile's loads NOW — latency hides under the store drain
        long long t_next = t + gridDim.x;
        if (t_next < ntiles) {
            long long row = t_next * TILE + tid;
            if (row < eh) {
                int s = src_h[row];
                int d = dst_h[row];
                unsigned int ps = pc[s];
                unsigned int pd = pc[d];
                int a = (int)(ps >> 2);
                int b = (int)(ps & 3u);
                int c = (int)(pd & 3u);
                my_combo = (unsigned char)(((a == c) << 2) | ((a == b) << 1) |
                                           (int)(b == c));
            }
        }

        // stream this tile's output (contiguous 64 KB, full cache lines)
        long long base = t * TILE;
        int nrows = (eh - base) < TILE ? (int)(eh - base) : TILE;
        int total4 = nrows << 4;           // nrows * 16 float4
        for (int j = tid; j < total4; j += blockDim.x) {
            nfloat4 v = table4[combo_s[j >> 4] * 16 + (j & 15)];
            __builtin_nontemporal_store(v, &out4[base * 16 + j]);
        }

        t = t_next;
        __syncthreads();                   // protect combo_s before overwrite
    }
}

extern "C" void kernel_launch(void* const* d_in, const int* in_sizes, int n_in,
                              void* d_out, int out_size, void* d_ws, size_t ws_size,
                              hipStream_t stream) {
    const int* h_nodes = (const int*)d_in[0];
    const int* src_g   = (const int*)d_in[1];
    const int* dst_g   = (const int*)d_in[2];
    const int* src_h   = (const int*)d_in[3];
    const int* dst_h   = (const int*)d_in[4];
    const float* e1_w  = (const float*)d_in[5];
    const float* e2_w  = (const float*)d_in[6];
    const float* e3_w  = (const float*)d_in[7];

    const int eg = in_sizes[1];   // E_G = 1,600,000
    const int eh = in_sizes[3];   // E_H = 2,000,000

    unsigned char* pc = (unsigned char*)d_ws;   // E_G bytes of scratch

    pack_edge_colors_kernel<<<1024, 256, 0, stream>>>(
        (const int4*)src_g, (const int4*)dst_g, src_g, dst_g, h_nodes, pc, eg);

    triplet_out_kernel<<<2048, 256, 0, stream>>>(src_h, dst_h, pc,
                                                 e1_w, e2_w, e3_w,
                                                 (float*)d_out, eh);
}